// Round 3
// baseline (484.535 us; speedup 1.0000x reference)
//
#include <hip/hip_runtime.h>
#include <hip/hip_bf16.h>
#include <stdint.h>

#define T_TOK 4096
#define H_DIM 1024
#define F_DIM 2816
#define NE 8

using bf16x8 = __attribute__((ext_vector_type(8))) short;   // 8 bf16 in 4 VGPRs
using f32x4  = __attribute__((ext_vector_type(4))) float;   // MFMA accumulator

#define WAITVM(N) asm volatile("s_waitcnt vmcnt(" #N ")" ::: "memory")

// RNE float -> bf16 bits (finite inputs only)
__device__ __forceinline__ unsigned short f2bf(float f) {
    union { float f; uint32_t u; } v; v.f = f;
    uint32_t r = v.u + 0x7FFFu + ((v.u >> 16) & 1u);
    return (unsigned short)(r >> 16);
}

// async global->LDS, 16B per lane. lds dest: wave-uniform base + lane*16.
__device__ __forceinline__ void gload_lds16(const void* gsrc, void* lds) {
    __builtin_amdgcn_global_load_lds(
        (const __attribute__((address_space(1))) uint32_t*)gsrc,
        (__attribute__((address_space(3))) uint32_t*)lds, 16, 0, 0);
}

// ---------------- router: one wave per token ----------------
__global__ __launch_bounds__(256) void router_kernel(
    const float* __restrict__ x, const float* __restrict__ wr,
    int* __restrict__ top_i, float* __restrict__ top_w, int* __restrict__ counts)
{
    const int w = threadIdx.x >> 6, l = threadIdx.x & 63;
    const int tok = blockIdx.x * 4 + w;
    const float* xrow = x + (size_t)tok * H_DIM;
    float acc[NE] = {};
    for (int h = l; h < H_DIM; h += 64) {
        float xv = xrow[h];
        const float* wrow = wr + h * NE;
#pragma unroll
        for (int e = 0; e < NE; e++) acc[e] += xv * wrow[e];
    }
#pragma unroll
    for (int e = 0; e < NE; e++) {
        for (int off = 32; off; off >>= 1) acc[e] += __shfl_xor(acc[e], off);
    }
    if (l == 0) {
        int i1 = 0; float b1 = acc[0];
#pragma unroll
        for (int e = 1; e < NE; e++) if (acc[e] > b1) { b1 = acc[e]; i1 = e; }
        int i2 = -1; float b2 = -1e30f;
#pragma unroll
        for (int e = 0; e < NE; e++) if (e != i1 && acc[e] > b2) { b2 = acc[e]; i2 = e; }
        float w1 = 1.0f / (1.0f + __expf(b2 - b1));   // exact renormalized top-2
        top_i[tok * 2] = i1; top_i[tok * 2 + 1] = i2;
        top_w[tok * 2] = w1; top_w[tok * 2 + 1] = 1.0f - w1;
        atomicAdd(&counts[i1], 1); atomicAdd(&counts[i2], 1);
    }
}

__global__ void prefix_kernel(const int* __restrict__ counts,
                              int* __restrict__ offsets, int* __restrict__ cursor)
{
    if (threadIdx.x == 0 && blockIdx.x == 0) {
        int s = 0;
        for (int e = 0; e < NE; e++) { offsets[e] = s; cursor[e] = s; s += counts[e]; }
        offsets[NE] = s;
    }
}

__global__ __launch_bounds__(256) void scatter_kernel(
    const int* __restrict__ top_i,
    int* __restrict__ cursor, int* __restrict__ pair_tok, int* __restrict__ inv_pos)
{
    int tok = blockIdx.x * 256 + threadIdx.x;
    if (tok < T_TOK) {
#pragma unroll
        for (int k = 0; k < 2; k++) {
            int e = top_i[tok * 2 + k];
            int pos = atomicAdd(&cursor[e], 1);
            pair_tok[pos] = tok;
            inv_pos[tok * 2 + k] = pos;
        }
    }
}

// ---------------- x f32 -> bf16 ----------------
__global__ __launch_bounds__(256) void cvt_x_kernel(const float* __restrict__ x,
                                                    unsigned short* __restrict__ xbf)
{
    int i = blockIdx.x * 256 + threadIdx.x;
    float4 v = ((const float4*)x)[i];
    ushort4 o;
    o.x = f2bf(v.x); o.y = f2bf(v.y); o.z = f2bf(v.z); o.w = f2bf(v.w);
    ((ushort4*)xbf)[i] = o;
}

// ---------------- batched transpose+cvt: in[e][R][C] f32 -> out[e][C][R] bf16 ----------------
// 64x64 tiles; bf16-pair packed u32 LDS (halves LDS traffic vs f32 tile).
__global__ __launch_bounds__(256) void transpose_cvt_v2(
    const float* __restrict__ in, unsigned short* __restrict__ outp, int R, int C)
{
    __shared__ uint32_t tile[64][33];
    const int e = blockIdx.z;
    const float* inp = in + (size_t)e * R * C;
    unsigned short* oute = outp + (size_t)e * R * C;
    const int c0 = blockIdx.x * 64, r0 = blockIdx.y * 64;
    const int t = threadIdx.x;
#pragma unroll
    for (int i = 0; i < 8; ++i) {
        int lin = i * 256 + t;
        int r = lin >> 5, cp = lin & 31;
        float2 v = *(const float2*)&inp[(size_t)(r0 + r) * C + c0 + cp * 2];
        tile[r][cp] = (uint32_t)f2bf(v.x) | ((uint32_t)f2bf(v.y) << 16);
    }
    __syncthreads();
#pragma unroll
    for (int q = 0; q < 4; ++q) {
        int oc = (t >> 4) + q * 16;
        int j = t & 15;
        int cp = oc >> 1, sh = (oc & 1) * 16;
        ushort4 o;
        o.x = (unsigned short)(tile[j * 4 + 0][cp] >> sh);
        o.y = (unsigned short)(tile[j * 4 + 1][cp] >> sh);
        o.z = (unsigned short)(tile[j * 4 + 2][cp] >> sh);
        o.w = (unsigned short)(tile[j * 4 + 3][cp] >> sh);
        *(ushort4*)&oute[(size_t)(c0 + oc) * R + r0 + j * 4] = o;
    }
}

// ---------------- GEMM1: 4-slab K-32-phase pipeline, 256x(128G+128U), fused silu*u ----------------
// slab (32KB) = A[256][32] + G[128][32] + U[128][32], 64B rows, chunk swizzle c^((row>>1)&3).
// phase u: vmcnt(12); barrier; 12 ds_read_b128; 32 MFMA; barrier; stage slab(u+4).
__global__ __launch_bounds__(512, 2) void gemm1_pipe8(
    const unsigned short* __restrict__ xbf,
    const unsigned short* __restrict__ wgT,
    const unsigned short* __restrict__ wuT,
    const int* __restrict__ pair_tok, const int* __restrict__ offsets,
    unsigned short* __restrict__ Abuf)
{
    // chunked XCD remap: work order = y fastest within (x,e); each XCD gets a contiguous chunk
    const int flat = blockIdx.x;                      // 22*32*8 = 5632
    const int wk = (flat & 7) * 704 + (flat >> 3);
    const int yy = wk & 31, rest = wk >> 5;
    const int xx = rest % 22, e = rest / 22;

    const int off = offsets[e], Ne = offsets[e + 1] - off;
    const int m0 = yy * 256;
    if (m0 >= Ne) return;
    const int bn0 = xx * 128;

    __shared__ char smem[131072];                     // 4 slabs x 32KB

    const int t = threadIdx.x, l = t & 63, w = t >> 6;
    const int llo = l & 15, lhi = l >> 4;
    const int wm = w >> 2, wn = w & 3;

    // staging sources (per thread, fixed row/chunk; k advances by stage index)
    const int sr0 = t >> 2, lc = t & 3;               // rows 0-127 (round0), +128 (round1)
    const int sr1 = 128 + sr0;
    int pr0 = m0 + sr0; if (pr0 > Ne - 1) pr0 = Ne - 1;
    int pr1 = m0 + sr1; if (pr1 > Ne - 1) pr1 = Ne - 1;
    const unsigned short* srcA0 = xbf + (size_t)pair_tok[off + pr0] * H_DIM + (lc ^ ((sr0 >> 1) & 3)) * 8;
    const unsigned short* srcA1 = xbf + (size_t)pair_tok[off + pr1] * H_DIM + (lc ^ ((sr1 >> 1) & 3)) * 8;
    const unsigned short* srcB0 = wgT + ((size_t)e * F_DIM + bn0 + sr0) * H_DIM + (lc ^ ((sr0 >> 1) & 3)) * 8;
    const unsigned short* srcB1 = wuT + ((size_t)e * F_DIM + bn0 + sr0) * H_DIM + (lc ^ ((sr0 >> 1) & 3)) * 8;

    auto STAGE = [&](int ti) {
        char* sb = smem + (ti & 3) * 32768;
        const int ko = ti * 32;
        gload_lds16(srcA0 + ko, sb + 0     + w * 1024);
        gload_lds16(srcA1 + ko, sb + 8192  + w * 1024);
        gload_lds16(srcB0 + ko, sb + 16384 + w * 1024);
        gload_lds16(srcB1 + ko, sb + 24576 + w * 1024);
    };

    // fragment LDS byte offsets (constant per thread)
    int aoff[8], goff[2];
#pragma unroll
    for (int m = 0; m < 8; ++m) {
        int row = wm * 128 + m * 16 + llo;
        aoff[m] = row * 64 + ((lhi ^ ((row >> 1) & 3)) * 16);
    }
#pragma unroll
    for (int n = 0; n < 2; ++n) {
        int g = wn * 32 + n * 16 + llo;
        goff[n] = g * 64 + ((lhi ^ ((g >> 1) & 3)) * 16);
    }

    f32x4 accG[8][2] = {}, accU[8][2] = {};

    auto COMPUTE = [&](int u) {
        __builtin_amdgcn_s_barrier();
        asm volatile("" ::: "memory");
        const char* sb = smem + (u & 3) * 32768;
        bf16x8 af[8], gf[2], uf[2];
#pragma unroll
        for (int m = 0; m < 8; ++m) af[m] = *(const bf16x8*)(sb + aoff[m]);
#pragma unroll
        for (int n = 0; n < 2; ++n) {
            gf[n] = *(const bf16x8*)(sb + 16384 + goff[n]);
            uf[n] = *(const bf16x8*)(sb + 24576 + goff[n]);
        }
        __builtin_amdgcn_s_setprio(1);
#pragma unroll
        for (int m = 0; m < 8; ++m)
#pragma unroll
            for (int n = 0; n < 2; ++n) {
                accG[m][n] = __builtin_amdgcn_mfma_f32_16x16x32_bf16(af[m], gf[n], accG[m][n], 0, 0, 0);
                accU[m][n] = __builtin_amdgcn_mfma_f32_16x16x32_bf16(af[m], uf[n], accU[m][n], 0, 0, 0);
            }
        __builtin_amdgcn_s_setprio(0);
        asm volatile("" ::: "memory");
        __builtin_amdgcn_s_barrier();
        asm volatile("" ::: "memory");
    };

    const int NPH = H_DIM / 32;   // 32
    STAGE(0); STAGE(1); STAGE(2); STAGE(3);
    for (int u = 0; u < NPH - 4; ++u) {
        WAITVM(12);
        COMPUTE(u);
        STAGE(u + 4);
    }
    WAITVM(12); COMPUTE(NPH - 4);
    WAITVM(8);  COMPUTE(NPH - 3);
    WAITVM(4);  COMPUTE(NPH - 2);
    WAITVM(0);  COMPUTE(NPH - 1);

    // epilogue: silu(g)*u -> bf16. C/D: col=lane&15, row=(lane>>4)*4+reg
#pragma unroll
    for (int m = 0; m < 8; ++m) {
#pragma unroll
        for (int r = 0; r < 4; ++r) {
            int grow = m0 + wm * 128 + m * 16 + lhi * 4 + r;
            if (grow < Ne) {
                size_t p = (size_t)(off + grow);
#pragma unroll
                for (int n = 0; n < 2; ++n) {
                    float g = accG[m][n][r], u = accU[m][n][r];
                    float a = g / (1.0f + __expf(-g)) * u;
                    Abuf[p * F_DIM + bn0 + wn * 32 + n * 16 + llo] = f2bf(a);
                }
            }
        }
    }
}

// ---------------- GEMM2: 4-slab K-64-phase pipeline, 128x128, writes dbuf f32 ----------------
// slab (32KB) = A[128][64] + B[128][64], 128B rows, chunk swizzle c^(row&7).
__global__ __launch_bounds__(512, 2) void gemm2_pipe8(
    const unsigned short* __restrict__ Abuf,
    const unsigned short* __restrict__ wdT,
    const int* __restrict__ offsets,
    float* __restrict__ dbuf)
{
    const int flat = blockIdx.x;                      // 8*64*8 = 4096
    const int wk = (flat & 7) * 512 + (flat >> 3);
    const int yy = wk & 63, rest = wk >> 6;
    const int xx = rest & 7, e = rest >> 3;

    const int off = offsets[e], Ne = offsets[e + 1] - off;
    const int m0 = yy * 128;
    if (m0 >= Ne) return;
    const int bn0 = xx * 128;

    __shared__ char smem[131072];

    const int t = threadIdx.x, l = t & 63, w = t >> 6;
    const int llo = l & 15, lhi = l >> 4;
    const int wm = w >> 2, wn = w & 3;

    const int sr0 = t >> 3, lc = t & 7;               // rows 0-63 (round0), +64 (round1)
    const int sr1 = 64 + sr0;
    int pr0 = m0 + sr0; if (pr0 > Ne - 1) pr0 = Ne - 1;
    int pr1 = m0 + sr1; if (pr1 > Ne - 1) pr1 = Ne - 1;
    const unsigned short* srcA0 = Abuf + (size_t)(off + pr0) * F_DIM + (lc ^ (sr0 & 7)) * 8;
    const unsigned short* srcA1 = Abuf + (size_t)(off + pr1) * F_DIM + (lc ^ (sr1 & 7)) * 8;
    const unsigned short* srcB0 = wdT + ((size_t)e * H_DIM + bn0 + sr0) * F_DIM + (lc ^ (sr0 & 7)) * 8;
    const unsigned short* srcB1 = wdT + ((size_t)e * H_DIM + bn0 + sr1) * F_DIM + (lc ^ (sr1 & 7)) * 8;

    auto STAGE = [&](int ti) {
        char* sb = smem + (ti & 3) * 32768;
        const int ko = ti * 64;
        gload_lds16(srcA0 + ko, sb + 0     + w * 1024);
        gload_lds16(srcA1 + ko, sb + 8192  + w * 1024);
        gload_lds16(srcB0 + ko, sb + 16384 + w * 1024);
        gload_lds16(srcB1 + ko, sb + 24576 + w * 1024);
    };

    int aoff[4][2], boff[2][2];
#pragma unroll
    for (int m = 0; m < 4; ++m) {
        int row = wm * 64 + m * 16 + llo;
#pragma unroll
        for (int k2 = 0; k2 < 2; ++k2)
            aoff[m][k2] = row * 128 + (((k2 * 4 + lhi) ^ (row & 7)) * 16);
    }
#pragma unroll
    for (int n = 0; n < 2; ++n) {
        int row = wn * 32 + n * 16 + llo;
#pragma unroll
        for (int k2 = 0; k2 < 2; ++k2)
            boff[n][k2] = row * 128 + (((k2 * 4 + lhi) ^ (row & 7)) * 16);
    }

    f32x4 acc[4][2] = {};

    auto COMPUTE = [&](int u) {
        __builtin_amdgcn_s_barrier();
        asm volatile("" ::: "memory");
        const char* sb = smem + (u & 3) * 32768;
        bf16x8 af[4][2], bf[2][2];
#pragma unroll
        for (int m = 0; m < 4; ++m)
#pragma unroll
            for (int k2 = 0; k2 < 2; ++k2) af[m][k2] = *(const bf16x8*)(sb + aoff[m][k2]);
#pragma unroll
        for (int n = 0; n < 2; ++n)
#pragma unroll
            for (int k2 = 0; k2 < 2; ++k2) bf[n][k2] = *(const bf16x8*)(sb + 16384 + boff[n][k2]);
        __builtin_amdgcn_s_setprio(1);
#pragma unroll
        for (int m = 0; m < 4; ++m)
#pragma unroll
            for (int n = 0; n < 2; ++n) {
                acc[m][n] = __builtin_amdgcn_mfma_f32_16x16x32_bf16(af[m][0], bf[n][0], acc[m][n], 0, 0, 0);
                acc[m][n] = __builtin_amdgcn_mfma_f32_16x16x32_bf16(af[m][1], bf[n][1], acc[m][n], 0, 0, 0);
            }
        __builtin_amdgcn_s_setprio(0);
        asm volatile("" ::: "memory");
        __builtin_amdgcn_s_barrier();
        asm volatile("" ::: "memory");
    };

    const int NPH = F_DIM / 64;   // 44
    STAGE(0); STAGE(1); STAGE(2); STAGE(3);
    for (int u = 0; u < NPH - 4; ++u) {
        WAITVM(12);
        COMPUTE(u);
        STAGE(u + 4);
    }
    WAITVM(12); COMPUTE(NPH - 4);
    WAITVM(8);  COMPUTE(NPH - 3);
    WAITVM(4);  COMPUTE(NPH - 2);
    WAITVM(0);  COMPUTE(NPH - 1);

#pragma unroll
    for (int m = 0; m < 4; ++m) {
#pragma unroll
        for (int r = 0; r < 4; ++r) {
            int grow = m0 + wm * 64 + m * 16 + lhi * 4 + r;
            if (grow < Ne) {
                size_t p = (size_t)(off + grow);
#pragma unroll
                for (int n = 0; n < 2; ++n)
                    dbuf[p * H_DIM + bn0 + wn * 32 + n * 16 + llo] = acc[m][n][r];
            }
        }
    }
}

// ---------------- combine: out[t] = w0*d[p0] + w1*d[p1] ----------------
__global__ __launch_bounds__(256) void combine_kernel(
    const float* __restrict__ dbuf, const int* __restrict__ inv_pos,
    const float* __restrict__ top_w, float* __restrict__ out)
{
    int tok = blockIdx.x;
    int p0 = inv_pos[tok * 2], p1 = inv_pos[tok * 2 + 1];
    float w0 = top_w[tok * 2], w1 = top_w[tok * 2 + 1];
    int c = threadIdx.x * 4;
    float4 a = *(const float4*)&dbuf[(size_t)p0 * H_DIM + c];
    float4 b = *(const float4*)&dbuf[(size_t)p1 * H_DIM + c];
    float4 o;
    o.x = w0 * a.x + w1 * b.x;
    o.y = w0 * a.y + w1 * b.y;
    o.z = w0 * a.z + w1 * b.z;
    o.w = w0 * a.w + w1 * b.w;
    *(float4*)&out[(size_t)tok * H_DIM + c] = o;
}

extern "C" void kernel_launch(void* const* d_in, const int* in_sizes, int n_in,
                              void* d_out, int out_size, void* d_ws, size_t ws_size,
                              hipStream_t stream)
{
    const float* x  = (const float*)d_in[0];
    const float* wr = (const float*)d_in[1];
    const float* wg = (const float*)d_in[2];
    const float* wu = (const float*)d_in[3];
    const float* wd = (const float*)d_in[4];
    float* out = (float*)d_out;

    char* ws = (char*)d_ws;
    const size_t WT = (size_t)NE * F_DIM * H_DIM * 2;            // 46,137,344 B
    unsigned short* wgT  = (unsigned short*)(ws);                // reused as wdT after gemm1
    unsigned short* wuT  = (unsigned short*)(ws + WT);           // reused as dbuf (f32) after gemm1
    unsigned short* Abuf = (unsigned short*)(ws + 2 * WT);
    unsigned short* xbf  = (unsigned short*)(ws + 3 * WT);
    char* misc = ws + 3 * WT + (size_t)T_TOK * H_DIM * 2;
    int*   pair_tok = (int*)(misc);
    int*   top_i    = (int*)(misc + 32768);
    float* top_w    = (float*)(misc + 65536);
    int*   inv_pos  = (int*)(misc + 98304);
    int*   counts   = (int*)(misc + 131072);
    int*   offsets  = counts + 8;
    int*   cursor   = offsets + 9;
    unsigned short* wdT = wgT;
    float* dbuf = (float*)wuT;

    hipMemsetAsync(counts, 0, 8 * sizeof(int), stream);

    cvt_x_kernel<<<T_TOK * H_DIM / (256 * 4), 256, 0, stream>>>(x, xbf);
    transpose_cvt_v2<<<dim3(F_DIM / 64, H_DIM / 64, NE), 256, 0, stream>>>(wg, wgT, H_DIM, F_DIM);
    transpose_cvt_v2<<<dim3(F_DIM / 64, H_DIM / 64, NE), 256, 0, stream>>>(wu, wuT, H_DIM, F_DIM);
    router_kernel<<<T_TOK / 4, 256, 0, stream>>>(x, wr, top_i, top_w, counts);
    prefix_kernel<<<1, 64, 0, stream>>>(counts, offsets, cursor);
    scatter_kernel<<<T_TOK / 256, 256, 0, stream>>>(top_i, cursor, pair_tok, inv_pos);
    gemm1_pipe8<<<22 * 32 * NE, 512, 0, stream>>>(xbf, wgT, wuT, pair_tok, offsets, Abuf);
    transpose_cvt_v2<<<dim3(H_DIM / 64, F_DIM / 64, NE), 256, 0, stream>>>(wd, wdT, F_DIM, H_DIM);
    gemm2_pipe8<<<8 * 64 * NE, 512, 0, stream>>>(Abuf, wdT, offsets, dbuf);
    combine_kernel<<<T_TOK, 256, 0, stream>>>(dbuf, inv_pos, top_w, out);
}

// Round 4
// 425.953 us; speedup vs baseline: 1.1375x; 1.1375x over previous
//
#include <hip/hip_runtime.h>
#include <hip/hip_bf16.h>
#include <stdint.h>

#define T_TOK 4096
#define H_DIM 1024
#define F_DIM 2816
#define NE 8
#define NTILE_MAX 72   // >= sum_e ceil(Ne/128) worst case (64 + 7 partials)

using bf16x8 = __attribute__((ext_vector_type(8))) short;   // 8 bf16 in 4 VGPRs
using f32x4  = __attribute__((ext_vector_type(4))) float;   // MFMA accumulator

// RNE float -> bf16 bits (finite inputs only)
__device__ __forceinline__ unsigned short f2bf(float f) {
    union { float f; uint32_t u; } v; v.f = f;
    uint32_t r = v.u + 0x7FFFu + ((v.u >> 16) & 1u);
    return (unsigned short)(r >> 16);
}

// async global->LDS, 16B per lane. lds dest: wave-uniform base + lane*16.
__device__ __forceinline__ void gload_lds16(const void* gsrc, void* lds) {
    __builtin_amdgcn_global_load_lds(
        (const __attribute__((address_space(1))) uint32_t*)gsrc,
        (__attribute__((address_space(3))) uint32_t*)lds, 16, 0, 0);
}

// ---------------- router: one wave per token ----------------
__global__ __launch_bounds__(256) void router_kernel(
    const float* __restrict__ x, const float* __restrict__ wr,
    int* __restrict__ top_i, float* __restrict__ top_w, int* __restrict__ counts)
{
    const int w = threadIdx.x >> 6, l = threadIdx.x & 63;
    const int tok = blockIdx.x * 4 + w;
    const float* xrow = x + (size_t)tok * H_DIM;
    float acc[NE] = {};
    for (int h = l; h < H_DIM; h += 64) {
        float xv = xrow[h];
        const float* wrow = wr + h * NE;
#pragma unroll
        for (int e = 0; e < NE; e++) acc[e] += xv * wrow[e];
    }
#pragma unroll
    for (int e = 0; e < NE; e++) {
        for (int off = 32; off; off >>= 1) acc[e] += __shfl_xor(acc[e], off);
    }
    if (l == 0) {
        int i1 = 0; float b1 = acc[0];
#pragma unroll
        for (int e = 1; e < NE; e++) if (acc[e] > b1) { b1 = acc[e]; i1 = e; }
        int i2 = -1; float b2 = -1e30f;
#pragma unroll
        for (int e = 0; e < NE; e++) if (e != i1 && acc[e] > b2) { b2 = acc[e]; i2 = e; }
        float w1 = 1.0f / (1.0f + __expf(b2 - b1));   // exact renormalized top-2
        top_i[tok * 2] = i1; top_i[tok * 2 + 1] = i2;
        top_w[tok * 2] = w1; top_w[tok * 2 + 1] = 1.0f - w1;
        atomicAdd(&counts[i1], 1); atomicAdd(&counts[i2], 1);
    }
}

// prefix + work-table: tile list of (expert, m-tile) pairs, 128 rows per tile
__global__ void prefix_kernel(const int* __restrict__ counts,
                              int* __restrict__ offsets, int* __restrict__ cursor,
                              int* __restrict__ wtab)
{
    if (threadIdx.x == 0 && blockIdx.x == 0) {
        int s = 0;
        for (int e = 0; e < NE; e++) { offsets[e] = s; cursor[e] = s; s += counts[e]; }
        offsets[NE] = s;
        int idx = 0;
        for (int e = 0; e < NE; e++) {
            int nt = (counts[e] + 127) >> 7;
            for (int mt = 0; mt < nt && idx < NTILE_MAX; ++mt) wtab[idx++] = (e << 16) | mt;
        }
        while (idx < NTILE_MAX) wtab[idx++] = -1;
    }
}

__global__ __launch_bounds__(256) void scatter_kernel(
    const int* __restrict__ top_i, const float* __restrict__ top_w,
    int* __restrict__ cursor, int* __restrict__ pair_tok, float* __restrict__ pair_w)
{
    int tok = blockIdx.x * 256 + threadIdx.x;
    if (tok < T_TOK) {
#pragma unroll
        for (int k = 0; k < 2; k++) {
            int e = top_i[tok * 2 + k];
            int pos = atomicAdd(&cursor[e], 1);
            pair_tok[pos] = tok;
            pair_w[pos] = top_w[tok * 2 + k];
        }
    }
}

// ---------------- x f32 -> bf16 (also zeroes out) ----------------
__global__ __launch_bounds__(256) void cvt_x_kernel(const float* __restrict__ x,
                                                    unsigned short* __restrict__ xbf)
{
    int i = blockIdx.x * 256 + threadIdx.x;
    float4 v = ((const float4*)x)[i];
    ushort4 o;
    o.x = f2bf(v.x); o.y = f2bf(v.y); o.z = f2bf(v.z); o.w = f2bf(v.w);
    ((ushort4*)xbf)[i] = o;
}

// ---------------- transpose+cvt generic: in[e][R][C] f32 -> out[e][C][R] bf16 ----------------
__global__ __launch_bounds__(256) void transpose_cvt_v2(
    const float* __restrict__ in, unsigned short* __restrict__ outp, int R, int C)
{
    __shared__ uint32_t tile[64][33];
    const int e = blockIdx.z;
    const float* inp = in + (size_t)e * R * C;
    unsigned short* oute = outp + (size_t)e * R * C;
    const int c0 = blockIdx.x * 64, r0 = blockIdx.y * 64;
    const int t = threadIdx.x;
#pragma unroll
    for (int i = 0; i < 8; ++i) {
        int lin = i * 256 + t;
        int r = lin >> 5, cp = lin & 31;
        float2 v = *(const float2*)&inp[(size_t)(r0 + r) * C + c0 + cp * 2];
        tile[r][cp] = (uint32_t)f2bf(v.x) | ((uint32_t)f2bf(v.y) << 16);
    }
    __syncthreads();
#pragma unroll
    for (int q = 0; q < 4; ++q) {
        int oc = (t >> 4) + q * 16;
        int j = t & 15;
        int cp = oc >> 1, sh = (oc & 1) * 16;
        ushort4 o;
        o.x = (unsigned short)(tile[j * 4 + 0][cp] >> sh);
        o.y = (unsigned short)(tile[j * 4 + 1][cp] >> sh);
        o.z = (unsigned short)(tile[j * 4 + 2][cp] >> sh);
        o.w = (unsigned short)(tile[j * 4 + 3][cp] >> sh);
        *(ushort4*)&oute[(size_t)(c0 + oc) * R + r0 + j * 4] = o;
    }
}

// gate+up in one launch: z<8 -> wg[e=z], z>=8 -> wu[e=z-8]; R=H, C=F
__global__ __launch_bounds__(256) void transpose_cvt_gu(
    const float* __restrict__ wg, const float* __restrict__ wu,
    unsigned short* __restrict__ wgT, unsigned short* __restrict__ wuT)
{
    __shared__ uint32_t tile[64][33];
    const int z = blockIdx.z;
    const int e = z & 7;
    const float* inp = (z < 8 ? wg : wu) + (size_t)e * H_DIM * F_DIM;
    unsigned short* oute = (z < 8 ? wgT : wuT) + (size_t)e * H_DIM * F_DIM;
    const int c0 = blockIdx.x * 64, r0 = blockIdx.y * 64;
    const int t = threadIdx.x;
#pragma unroll
    for (int i = 0; i < 8; ++i) {
        int lin = i * 256 + t;
        int r = lin >> 5, cp = lin & 31;
        float2 v = *(const float2*)&inp[(size_t)(r0 + r) * F_DIM + c0 + cp * 2];
        tile[r][cp] = (uint32_t)f2bf(v.x) | ((uint32_t)f2bf(v.y) << 16);
    }
    __syncthreads();
#pragma unroll
    for (int q = 0; q < 4; ++q) {
        int oc = (t >> 4) + q * 16;
        int j = t & 15;
        int cp = oc >> 1, sh = (oc & 1) * 16;
        ushort4 o;
        o.x = (unsigned short)(tile[j * 4 + 0][cp] >> sh);
        o.y = (unsigned short)(tile[j * 4 + 1][cp] >> sh);
        o.z = (unsigned short)(tile[j * 4 + 2][cp] >> sh);
        o.w = (unsigned short)(tile[j * 4 + 3][cp] >> sh);
        *(ushort4*)&oute[(size_t)(c0 + oc) * H_DIM + r0 + j * 4] = o;
    }
}

// ---------------- GEMM1: m97-style, 128 rows x 64 f (gate+up), BK=64, 32KB LDS ----------------
// LDS: sA[128][64] 16KB | sG[64][64] 8KB | sU[64][64] 8KB. chunk swizzle c^(row&7).
__global__ __launch_bounds__(256, 4) void gemm1_kernel(
    const unsigned short* __restrict__ xbf,
    const unsigned short* __restrict__ wgT,
    const unsigned short* __restrict__ wuT,
    const int* __restrict__ pair_tok, const int* __restrict__ offsets,
    const int* __restrict__ wtab,
    unsigned short* __restrict__ Abuf)
{
    const int wv = wtab[blockIdx.y];
    if (wv < 0) return;
    const int e = wv >> 16;
    const int m0 = (wv & 0xFFFF) * 128;
    const int off = offsets[e], Ne = offsets[e + 1] - off;
    const int bn0 = blockIdx.x * 64;

    __shared__ unsigned short smem[16384];   // 32KB
    unsigned short* sA = smem;               // bytes [0, 16384)
    char* sG = (char*)smem + 16384;          // [16384, 24576)
    char* sU = (char*)smem + 24576;          // [24576, 32768)

    const int t = threadIdx.x, l = t & 63, w = t >> 6;
    const int llo = l & 15, lhi = l >> 4;
    const int wm = w >> 1, wn = w & 1;
    const int slr = l >> 3, slc = l & 7;     // staging: row-in-seg, chunk

    // staging sources: A = 16 segs (4/wave), G/U = 8 segs (2/wave). seg = 8 rows x 128B.
    const unsigned short* srcA[4];
#pragma unroll
    for (int i = 0; i < 4; ++i) {
        int s = w * 4 + i;
        int r = s * 8 + slr;
        int pr = m0 + r; if (pr > Ne - 1) pr = Ne - 1;
        srcA[i] = xbf + (size_t)pair_tok[off + pr] * H_DIM + (slc ^ (r & 7)) * 8;
    }
    const unsigned short* srcG[2];
    const unsigned short* srcU[2];
#pragma unroll
    for (int i = 0; i < 2; ++i) {
        int s = w * 2 + i;
        int fr = s * 8 + slr;
        srcG[i] = wgT + ((size_t)e * F_DIM + bn0 + fr) * H_DIM + (slc ^ (fr & 7)) * 8;
        srcU[i] = wuT + ((size_t)e * F_DIM + bn0 + fr) * H_DIM + (slc ^ (fr & 7)) * 8;
    }

    // fragment byte offsets
    int aoff[4][2], goff[2][2];
#pragma unroll
    for (int m = 0; m < 4; ++m) {
        int row = wm * 64 + m * 16 + llo;
#pragma unroll
        for (int kk = 0; kk < 2; ++kk)
            aoff[m][kk] = row * 128 + (((kk * 4 + lhi) ^ (row & 7)) * 16);
    }
#pragma unroll
    for (int n = 0; n < 2; ++n) {
        int g = wn * 32 + n * 16 + llo;
#pragma unroll
        for (int kk = 0; kk < 2; ++kk)
            goff[n][kk] = g * 128 + (((kk * 4 + lhi) ^ (g & 7)) * 16);
    }

    f32x4 accG[4][2] = {}, accU[4][2] = {};

    for (int k0 = 0; k0 < H_DIM; k0 += 64) {
        __syncthreads();
#pragma unroll
        for (int i = 0; i < 4; ++i)
            gload_lds16(srcA[i] + k0, (char*)sA + (w * 4 + i) * 1024);
#pragma unroll
        for (int i = 0; i < 2; ++i) {
            gload_lds16(srcG[i] + k0, sG + (w * 2 + i) * 1024);
            gload_lds16(srcU[i] + k0, sU + (w * 2 + i) * 1024);
        }
        asm volatile("s_waitcnt vmcnt(0)" ::: "memory");
        __syncthreads();

#pragma unroll
        for (int kk = 0; kk < 2; ++kk) {
            bf16x8 af[4], gf[2], uf[2];
#pragma unroll
            for (int m = 0; m < 4; ++m) af[m] = *(const bf16x8*)((const char*)sA + aoff[m][kk]);
#pragma unroll
            for (int n = 0; n < 2; ++n) {
                gf[n] = *(const bf16x8*)(sG + goff[n][kk]);
                uf[n] = *(const bf16x8*)(sU + goff[n][kk]);
            }
            __builtin_amdgcn_s_setprio(1);
#pragma unroll
            for (int m = 0; m < 4; ++m)
#pragma unroll
                for (int n = 0; n < 2; ++n) {
                    accG[m][n] = __builtin_amdgcn_mfma_f32_16x16x32_bf16(af[m], gf[n], accG[m][n], 0, 0, 0);
                    accU[m][n] = __builtin_amdgcn_mfma_f32_16x16x32_bf16(af[m], uf[n], accU[m][n], 0, 0, 0);
                }
            __builtin_amdgcn_s_setprio(0);
        }
    }

    // epilogue: silu(g)*u -> bf16. C/D: col=lane&15, row=(lane>>4)*4+reg
#pragma unroll
    for (int m = 0; m < 4; ++m) {
#pragma unroll
        for (int r = 0; r < 4; ++r) {
            int grow = m0 + wm * 64 + m * 16 + lhi * 4 + r;
            if (grow < Ne) {
                size_t p = (size_t)(off + grow);
#pragma unroll
                for (int n = 0; n < 2; ++n) {
                    float g = accG[m][n][r], u = accU[m][n][r];
                    float a = g / (1.0f + __expf(-g)) * u;
                    Abuf[p * F_DIM + bn0 + wn * 32 + n * 16 + llo] = f2bf(a);
                }
            }
        }
    }
}

// ---------------- GEMM2: m97-style, 128 x 128, BK=64, 32KB LDS, atomic combine ----------------
__global__ __launch_bounds__(256, 4) void gemm2_kernel(
    const unsigned short* __restrict__ Abuf,
    const unsigned short* __restrict__ wdT,
    const int* __restrict__ pair_tok, const float* __restrict__ pair_w,
    const int* __restrict__ offsets, const int* __restrict__ wtab,
    float* __restrict__ out)
{
    const int wv = wtab[blockIdx.y];
    if (wv < 0) return;
    const int e = wv >> 16;
    const int m0 = (wv & 0xFFFF) * 128;
    const int off = offsets[e], Ne = offsets[e + 1] - off;
    const int bn0 = blockIdx.x * 128;

    __shared__ unsigned short smem[16384];   // 32KB: A 16KB | B 16KB
    unsigned short* sA = smem;
    char* sB = (char*)smem + 16384;

    const int t = threadIdx.x, l = t & 63, w = t >> 6;
    const int llo = l & 15, lhi = l >> 4;
    const int wm = w >> 1, wn = w & 1;
    const int slr = l >> 3, slc = l & 7;

    const unsigned short* srcA[4];
    const unsigned short* srcB[4];
#pragma unroll
    for (int i = 0; i < 4; ++i) {
        int s = w * 4 + i;
        int r = s * 8 + slr;
        int pr = m0 + r; if (pr > Ne - 1) pr = Ne - 1;
        srcA[i] = Abuf + (size_t)(off + pr) * F_DIM + (slc ^ (r & 7)) * 8;
        srcB[i] = wdT + ((size_t)e * H_DIM + bn0 + r) * F_DIM + (slc ^ (r & 7)) * 8;
    }

    int aoff[4][2], boff[4][2];
#pragma unroll
    for (int m = 0; m < 4; ++m) {
        int row = wm * 64 + m * 16 + llo;
        int brow = wn * 64 + m * 16 + llo;
#pragma unroll
        for (int kk = 0; kk < 2; ++kk) {
            aoff[m][kk] = row * 128 + (((kk * 4 + lhi) ^ (row & 7)) * 16);
            boff[m][kk] = brow * 128 + (((kk * 4 + lhi) ^ (brow & 7)) * 16);
        }
    }

    f32x4 acc[4][4] = {};

    for (int k0 = 0; k0 < F_DIM; k0 += 64) {
        __syncthreads();
#pragma unroll
        for (int i = 0; i < 4; ++i) {
            gload_lds16(srcA[i] + k0, (char*)sA + (w * 4 + i) * 1024);
            gload_lds16(srcB[i] + k0, sB + (w * 4 + i) * 1024);
        }
        asm volatile("s_waitcnt vmcnt(0)" ::: "memory");
        __syncthreads();

#pragma unroll
        for (int kk = 0; kk < 2; ++kk) {
            bf16x8 af[4], bfr[4];
#pragma unroll
            for (int m = 0; m < 4; ++m) {
                af[m]  = *(const bf16x8*)((const char*)sA + aoff[m][kk]);
                bfr[m] = *(const bf16x8*)(sB + boff[m][kk]);
            }
            __builtin_amdgcn_s_setprio(1);
#pragma unroll
            for (int m = 0; m < 4; ++m)
#pragma unroll
                for (int n = 0; n < 4; ++n)
                    acc[m][n] = __builtin_amdgcn_mfma_f32_16x16x32_bf16(af[m], bfr[n], acc[m][n], 0, 0, 0);
            __builtin_amdgcn_s_setprio(0);
        }
    }

    // epilogue: out[tok] += w * acc (exactly 2 adds per element -> deterministic)
#pragma unroll
    for (int m = 0; m < 4; ++m) {
#pragma unroll
        for (int r = 0; r < 4; ++r) {
            int grow = m0 + wm * 64 + m * 16 + lhi * 4 + r;
            if (grow < Ne) {
                int p = off + grow;
                int tok = pair_tok[p];
                float wgt = pair_w[p];
                float* orow = out + (size_t)tok * H_DIM + bn0 + wn * 64;
#pragma unroll
                for (int n = 0; n < 4; ++n)
                    atomicAdd(orow + n * 16 + llo, wgt * acc[m][n][r]);
            }
        }
    }
}

extern "C" void kernel_launch(void* const* d_in, const int* in_sizes, int n_in,
                              void* d_out, int out_size, void* d_ws, size_t ws_size,
                              hipStream_t stream)
{
    const float* x  = (const float*)d_in[0];
    const float* wr = (const float*)d_in[1];
    const float* wg = (const float*)d_in[2];
    const float* wu = (const float*)d_in[3];
    const float* wd = (const float*)d_in[4];
    float* out = (float*)d_out;

    char* ws = (char*)d_ws;
    const size_t WT = (size_t)NE * F_DIM * H_DIM * 2;            // 46,137,344 B
    unsigned short* wgT  = (unsigned short*)(ws);                // reused as wdT after gemm1
    unsigned short* wuT  = (unsigned short*)(ws + WT);
    unsigned short* Abuf = (unsigned short*)(ws + 2 * WT);
    unsigned short* xbf  = (unsigned short*)(ws + 3 * WT);
    char* misc = ws + 3 * WT + (size_t)T_TOK * H_DIM * 2;
    int*   pair_tok = (int*)(misc);
    float* pair_w   = (float*)(misc + 32768);
    int*   top_i    = (int*)(misc + 65536);
    float* top_w    = (float*)(misc + 98304);
    int*   counts   = (int*)(misc + 131072);
    int*   offsets  = counts + 8;
    int*   cursor   = offsets + 9;
    int*   wtab     = cursor + 8;
    unsigned short* wdT = wgT;

    hipMemsetAsync(counts, 0, 8 * sizeof(int), stream);
    hipMemsetAsync(out, 0, (size_t)T_TOK * H_DIM * sizeof(float), stream);

    cvt_x_kernel<<<T_TOK * H_DIM / (256 * 4), 256, 0, stream>>>(x, xbf);
    transpose_cvt_gu<<<dim3(F_DIM / 64, H_DIM / 64, 16), 256, 0, stream>>>(wg, wu, wgT, wuT);
    router_kernel<<<T_TOK / 4, 256, 0, stream>>>(x, wr, top_i, top_w, counts);
    prefix_kernel<<<1, 64, 0, stream>>>(counts, offsets, cursor, wtab);
    scatter_kernel<<<T_TOK / 256, 256, 0, stream>>>(top_i, top_w, cursor, pair_tok, pair_w);
    gemm1_kernel<<<dim3(F_DIM / 64, NTILE_MAX), 256, 0, stream>>>(xbf, wgT, wuT, pair_tok, offsets, wtab, Abuf);
    transpose_cvt_v2<<<dim3(H_DIM / 64, F_DIM / 64, NE), 256, 0, stream>>>(wd, wdT, F_DIM, H_DIM);
    gemm2_kernel<<<dim3(H_DIM / 128, NTILE_MAX), 256, 0, stream>>>(Abuf, wdT, pair_tok, pair_w, offsets, wtab, out);
}